// Round 2
// baseline (1113.090 us; speedup 1.0000x reference)
//
#include <hip/hip_runtime.h>
#include <math.h>

// ---- problem constants ----
constexpr int kHF = 361, kWF = 720;       // full grid
constexpr int kHP = 90,  kWP = 180;       // processor grid
constexpr int kCIN = 26, kCE = 48, kCOUT = 24;
constexpr int kK = 9, kNB = 6;
constexpr int kL = 90, kM = 90;
constexpr int kNL = 4, kHD = 96;
constexpr int kNP  = kHP * kWP;           // 16200
constexpr int kNPF = kHF * kWF;           // 259920

#ifndef M_PI
#define M_PI 3.14159265358979323846
#endif

// ---------------- precompute: DFT tables ----------------
__global__ __launch_bounds__(256) void k_tables(float* __restrict__ fc, float* __restrict__ fs,
                                                float* __restrict__ ic, float* __restrict__ isn) {
    int t = blockIdx.x * 256 + threadIdx.x;
    if (t >= kM * kWP) return;
    int m = t / kWP, w = t % kWP;
    double th = (2.0 * M_PI / (double)kWP) * (double)(m * w);
    double c = cos(th), s = sin(th);
    fc[w * kM + m] = (float)(c / (double)kWP);
    fs[w * kM + m] = (float)(-s / (double)kWP);
    float sc = (m == 0) ? 1.0f : 2.0f;
    ic[m * kWP + w] = sc * (float)c;
    isn[m * kWP + w] = sc * (float)s;
}

// transpose Legendre matrices for coalesced m-reads
__global__ __launch_bounds__(256) void k_trans(const float* __restrict__ P, float* __restrict__ PT, int mode) {
    int t = blockIdx.x * 256 + threadIdx.x;
    if (t >= kL * kM * kHP) return;
    int l = t / (kM * kHP);
    int r = t % (kM * kHP);
    int m = r / kHP;
    int tt = r % kHP;
    float v = P[t];
    if (mode == 0) PT[(l * kHP + tt) * kM + m] = v;
    else           PT[(tt * kL + l) * kM + m] = v;
}

// decoder weight transpose: dwT[(i*24 + o)*9 + k] = dw[(o*48+i)*9+k]
// -> per (i, og) the 12x9=108 weights are contiguous (scalar-load friendly)
__global__ __launch_bounds__(256) void k_wtrans(const float* __restrict__ dw, float* __restrict__ dwT) {
    int t = blockIdx.x * 256 + threadIdx.x;
    if (t >= kCOUT * kCE * kK) return;
    int k = t % kK;
    int i = (t / kK) % kCE;
    int o = t / (kK * kCE);
    dwT[((size_t)i * kCOUT + o) * kK + k] = dw[t];
}

// ---------------- disco conv (encoder / processor) ----------------
// y[o,p] = sum_{i,k} w[o,i,k] * sum_n vals[k,p,n] * src[i, idx[p,n]]
template <int TCIN, int TCOUT, int OG>
__global__ __launch_bounds__(256) void k_disco(const float* __restrict__ src, int srcStride,
                                               const int* __restrict__ idx, const float* __restrict__ vals,
                                               const float* __restrict__ w, float* __restrict__ out, int np) {
    int gt = blockIdx.x * 256 + threadIdx.x;
    if (gt >= np * OG) return;
    int p = gt % np;
    int og = gt / np;
    constexpr int OC = TCOUT / OG;

    int qi[kNB];
#pragma unroll
    for (int n = 0; n < kNB; n++) qi[n] = idx[p * kNB + n];

    // hoist vals[k,p,n] into registers (they do not depend on i)
    float vv[kK][kNB];
#pragma unroll
    for (int k = 0; k < kK; k++) {
        const float* vp = vals + ((size_t)k * np + p) * kNB;
#pragma unroll
        for (int n = 0; n < kNB; n += 2) {
            float2 v2 = *(const float2*)(vp + n);
            vv[k][n] = v2.x; vv[k][n + 1] = v2.y;
        }
    }

    float acc[OC];
#pragma unroll
    for (int o = 0; o < OC; o++) acc[o] = 0.0f;

    const float* wbase = w + (size_t)og * OC * TCIN * kK;

    for (int i = 0; i < TCIN; i++) {
        float xg[kNB];
#pragma unroll
        for (int n = 0; n < kNB; n++) xg[n] = src[i * srcStride + qi[n]];
        float z[kK];
#pragma unroll
        for (int k = 0; k < kK; k++) {
            float zz = 0.0f;
#pragma unroll
            for (int n = 0; n < kNB; n++) zz = fmaf(vv[k][n], xg[n], zz);
            z[k] = zz;
        }
#pragma unroll
        for (int o = 0; o < OC; o++) {
            const float* wp = wbase + ((size_t)o * TCIN + i) * kK;
            float s = acc[o];
#pragma unroll
            for (int k = 0; k < kK; k++) s = fmaf(wp[k], z[k], s);
            acc[o] = s;
        }
    }
#pragma unroll
    for (int o = 0; o < OC; o++) out[(size_t)(og * OC + o) * np + p] = acc[o];
}

// ---------------- spectral pipeline ----------------
__global__ __launch_bounds__(256) void k_rfft(const float* __restrict__ g, const float* __restrict__ fc,
                                              const float* __restrict__ fs, float* __restrict__ xre,
                                              float* __restrict__ xim) {
    int t = blockIdx.x * 256 + threadIdx.x;
    if (t >= kCE * kHP * kM) return;
    int m = t % kM;
    int row = t / kM;
    const float* gr = g + (size_t)row * kWP;
    float ar = 0.0f, ai = 0.0f;
    for (int w = 0; w < kWP; w++) {
        float gv = gr[w];
        ar = fmaf(gv, fc[w * kM + m], ar);
        ai = fmaf(gv, fs[w * kM + m], ai);
    }
    xre[t] = ar;
    xim[t] = ai;
}

__global__ __launch_bounds__(256) void k_sht(const float* __restrict__ PwT, const float* __restrict__ xre,
                                             const float* __restrict__ xim, float* __restrict__ cre,
                                             float* __restrict__ cim) {
    int t = blockIdx.x * 256 + threadIdx.x;
    if (t >= kCE * kL * kM) return;
    int m = t % kM;
    int l = (t / kM) % kL;
    int c = t / (kM * kL);
    float ar = 0.0f, ai = 0.0f;
    for (int tt = 0; tt < kHP; tt++) {
        float pv = PwT[((size_t)l * kHP + tt) * kM + m];
        ar = fmaf(pv, xre[((size_t)c * kHP + tt) * kM + m], ar);
        ai = fmaf(pv, xim[((size_t)c * kHP + tt) * kM + m], ai);
    }
    cre[t] = ar;
    cim[t] = ai;
}

__global__ __launch_bounds__(256) void k_gmix(const float* __restrict__ gwl, const float* __restrict__ cre,
                                              const float* __restrict__ cim, float* __restrict__ ore,
                                              float* __restrict__ oim) {
    int t = blockIdx.x * 256 + threadIdx.x;
    if (t >= kCE * kL * kM) return;
    int m = t % kM;
    int l = (t / kM) % kL;
    int o = t / (kM * kL);
    float ar = 0.0f, ai = 0.0f;
    for (int i = 0; i < kCE; i++) {
        float gv = gwl[((size_t)o * kCE + i) * kL + l];
        ar = fmaf(gv, cre[((size_t)i * kL + l) * kM + m], ar);
        ai = fmaf(gv, cim[((size_t)i * kL + l) * kM + m], ai);
    }
    ore[t] = ar;
    oim[t] = ai;
}

__global__ __launch_bounds__(256) void k_isht(const float* __restrict__ PiT, const float* __restrict__ cre,
                                              const float* __restrict__ cim, float* __restrict__ xre,
                                              float* __restrict__ xim) {
    int t = blockIdx.x * 256 + threadIdx.x;
    if (t >= kCE * kHP * kM) return;
    int m = t % kM;
    int tt = (t / kM) % kHP;
    int c = t / (kM * kHP);
    float ar = 0.0f, ai = 0.0f;
    for (int l = 0; l < kL; l++) {
        float pv = PiT[((size_t)tt * kL + l) * kM + m];
        ar = fmaf(pv, cre[((size_t)c * kL + l) * kM + m], ar);
        ai = fmaf(pv, cim[((size_t)c * kL + l) * kM + m], ai);
    }
    xre[t] = ar;
    xim[t] = ai;
}

__global__ __launch_bounds__(256) void k_irfft(const float* __restrict__ xre, const float* __restrict__ xim,
                                               const float* __restrict__ ic, const float* __restrict__ isn,
                                               float* __restrict__ dx) {
    int t = blockIdx.x * 256 + threadIdx.x;
    if (t >= kCE * kHP * kWP) return;
    int w = t % kWP;
    int row = t / kWP;
    const float* xr = xre + (size_t)row * kM;
    const float* xi = xim + (size_t)row * kM;
    float a = 0.0f;
    for (int m = 0; m < kM; m++) {
        a = fmaf(xr[m], ic[m * kWP + w], a);
        a = fmaf(-xi[m], isn[m * kWP + w], a);
    }
    dx[t] = a;
}

// ---------------- MLP ----------------
__device__ __forceinline__ float gelu_tanh(float x) {
    float x3 = x * x * x;
    float t = tanhf(0.7978845608028654f * (x + 0.044715f * x3));
    return 0.5f * x * (1.0f + t);
}

__global__ __launch_bounds__(256) void k_mlp1(const float* __restrict__ m1w, const float* __restrict__ dx,
                                              float* __restrict__ dx1) {
    int t = blockIdx.x * 256 + threadIdx.x;
    if (t >= kHD * kNP) return;
    int p = t % kNP;
    int hh = t / kNP;
    float a = 0.0f;
    for (int i = 0; i < kCE; i++) a = fmaf(m1w[hh * kCE + i], dx[(size_t)i * kNP + p], a);
    dx1[t] = gelu_tanh(a);
}

__global__ __launch_bounds__(256) void k_mlp2(const float* __restrict__ m2w, const float* __restrict__ lsw,
                                              const float* __restrict__ dx1, float* __restrict__ h) {
    int t = blockIdx.x * 256 + threadIdx.x;
    if (t >= kCE * kNP) return;
    int p = t % kNP;
    int o = t / kNP;
    float a = 0.0f;
    for (int j = 0; j < kHD; j++) a = fmaf(m2w[o * kHD + j], dx1[(size_t)j * kNP + p], a);
    h[t] = h[t] + lsw[o] * a;
}

// ---------------- decoder stage A: bilinear upsample h(90x180) -> u(361x720) ----------------
__global__ __launch_bounds__(256) void k_upsample(const float* __restrict__ h,
                                                  const int* __restrict__ li0, const int* __restrict__ li1,
                                                  const float* __restrict__ lwt, const int* __restrict__ oi0,
                                                  const int* __restrict__ oi1, const float* __restrict__ owt,
                                                  float* __restrict__ u) {
    int t = blockIdx.x * 256 + threadIdx.x;
    if (t >= kCE * kNPF) return;
    int pf = t % kNPF;
    int i = t / kNPF;
    int lat = pf / kWF;
    int lon = pf - lat * kWF;
    int a0 = li0[lat], a1 = li1[lat];
    float aw = lwt[lat];
    int o0 = oi0[lon], o1 = oi1[lon];
    float ow = owt[lon];
    const float* hi = h + (size_t)i * kNP;
    float v00 = hi[a0 * kWP + o0], v10 = hi[a1 * kWP + o0];
    float v01 = hi[a0 * kWP + o1], v11 = hi[a1 * kWP + o1];
    float c0 = fmaf(aw, v10 - v00, v00);
    float c1 = fmaf(aw, v11 - v01, v01);
    u[t] = fmaf(ow, c1 - c0, c0);
}

// ---------------- decoder stage B: disco conv on full grid ----------------
// OG=2: each thread computes 12 of 24 outputs for one point.
// weights dwT[(i*24+o)*9+k]: per (i, og) contiguous 108 floats, uniform address -> scalar loads.
__global__ __launch_bounds__(256, 4) void k_dconv(const float* __restrict__ u, const int* __restrict__ didx,
                                                  const float* __restrict__ dvals, const float* __restrict__ dwT,
                                                  float* __restrict__ out) {
    constexpr int OG = 2, OC = kCOUT / OG;  // 12
    int gt = blockIdx.x * 256 + threadIdx.x;
    if (gt >= kNPF * OG) return;
    int p = gt % kNPF;
    int og = gt / kNPF;

    int qi[kNB];
#pragma unroll
    for (int n = 0; n < kNB; n++) qi[n] = didx[p * kNB + n];

    // vals in registers (independent of i)
    float vv[kK][kNB];
#pragma unroll
    for (int k = 0; k < kK; k++) {
        const float* vp = dvals + ((size_t)k * kNPF + p) * kNB;
#pragma unroll
        for (int n = 0; n < kNB; n += 2) {
            float2 v2 = *(const float2*)(vp + n);
            vv[k][n] = v2.x; vv[k][n + 1] = v2.y;
        }
    }

    float acc[OC];
#pragma unroll
    for (int o = 0; o < OC; o++) acc[o] = 0.0f;

    for (int i = 0; i < kCE; i++) {
        const float* ui = u + (size_t)i * kNPF;
        float xg[kNB];
#pragma unroll
        for (int n = 0; n < kNB; n++) xg[n] = ui[qi[n]];
        float z[kK];
#pragma unroll
        for (int k = 0; k < kK; k++) {
            float zz = 0.0f;
#pragma unroll
            for (int n = 0; n < kNB; n++) zz = fmaf(vv[k][n], xg[n], zz);
            z[k] = zz;
        }
        const float* wp = dwT + ((size_t)i * kCOUT + og * OC) * kK;
#pragma unroll
        for (int o = 0; o < OC; o++) {
            float s = acc[o];
#pragma unroll
            for (int k = 0; k < kK; k++) s = fmaf(wp[o * kK + k], z[k], s);
            acc[o] = s;
        }
    }
#pragma unroll
    for (int o = 0; o < OC; o++) out[(size_t)(og * OC + o) * kNPF + p] = acc[o];
}

// ---------------- host launcher ----------------
extern "C" void kernel_launch(void* const* d_in, const int* in_sizes, int n_in,
                              void* d_out, int out_size, void* d_ws, size_t ws_size,
                              hipStream_t stream) {
    const float* x         = (const float*)d_in[0];
    const int*   enc_idx   = (const int*)d_in[1];
    const float* enc_vals  = (const float*)d_in[2];
    const float* enc_w     = (const float*)d_in[3];
    const int*   proc_idx  = (const int*)d_in[4];
    const float* proc_vals = (const float*)d_in[5];
    const float* lw        = (const float*)d_in[6];
    const float* gw        = (const float*)d_in[7];
    const float* Pw        = (const float*)d_in[8];
    const float* Pi        = (const float*)d_in[9];
    const float* m1        = (const float*)d_in[10];
    const float* m2        = (const float*)d_in[11];
    const float* ls        = (const float*)d_in[12];
    const int*   li0       = (const int*)d_in[13];
    const int*   li1       = (const int*)d_in[14];
    const float* lwt       = (const float*)d_in[15];
    const int*   oi0       = (const int*)d_in[16];
    const int*   oi1       = (const int*)d_in[17];
    const float* owt       = (const float*)d_in[18];
    const int*   dec_idx   = (const int*)d_in[19];
    const float* dec_vals  = (const float*)d_in[20];
    const float* dec_w     = (const float*)d_in[21];
    float* out = (float*)d_out;

    float* ws = (float*)d_ws;
    size_t off = 0;
    auto alloc = [&](size_t n) { float* p = ws + off; off += n; return p; };
    float* h    = alloc((size_t)kCE * kNP);
    float* xre  = alloc((size_t)kCE * kHP * kM);
    float* xim  = alloc((size_t)kCE * kHP * kM);
    float* cre  = alloc((size_t)kCE * kL * kM);
    float* cim  = alloc((size_t)kCE * kL * kM);
    float* c2re = alloc((size_t)kCE * kL * kM);
    float* c2im = alloc((size_t)kCE * kL * kM);
    float* dx   = alloc((size_t)kCE * kNP);
    float* dx1  = alloc((size_t)kHD * kNP);
    float* fc   = alloc((size_t)kM * kWP);
    float* fs   = alloc((size_t)kM * kWP);
    float* ic   = alloc((size_t)kM * kWP);
    float* isn  = alloc((size_t)kM * kWP);
    float* PwT  = alloc((size_t)kL * kM * kHP);
    float* PiT  = alloc((size_t)kL * kM * kHP);
    float* dwT  = alloc((size_t)kCOUT * kCE * kK);
    float* u    = alloc((size_t)kCE * kNPF);   // 50 MB
    (void)ws_size; (void)in_sizes; (void)n_in; (void)out_size;

    dim3 B(256);
    auto nb = [](long long n) { return dim3((unsigned)((n + 255) / 256)); };

    k_tables<<<nb(kM * kWP), B, 0, stream>>>(fc, fs, ic, isn);
    k_trans<<<nb((long long)kL * kM * kHP), B, 0, stream>>>(Pw, PwT, 0);
    k_trans<<<nb((long long)kL * kM * kHP), B, 0, stream>>>(Pi, PiT, 1);
    k_wtrans<<<nb((long long)kCOUT * kCE * kK), B, 0, stream>>>(dec_w, dwT);

    // encoder
    k_disco<kCIN, kCE, 8><<<nb((long long)kNP * 8), B, 0, stream>>>(
        x, kNPF, enc_idx, enc_vals, enc_w, h, kNP);

    for (int i = 0; i < kNL; i++) {
        if (i % 2 == 0) {
            const float* gwl = gw + (size_t)(i / 2) * kCE * kCE * kL;
            k_rfft<<<nb((long long)kCE * kHP * kM), B, 0, stream>>>(h, fc, fs, xre, xim);
            k_sht<<<nb((long long)kCE * kL * kM), B, 0, stream>>>(PwT, xre, xim, cre, cim);
            k_gmix<<<nb((long long)kCE * kL * kM), B, 0, stream>>>(gwl, cre, cim, c2re, c2im);
            k_isht<<<nb((long long)kCE * kHP * kM), B, 0, stream>>>(PiT, c2re, c2im, xre, xim);
            k_irfft<<<nb((long long)kCE * kHP * kWP), B, 0, stream>>>(xre, xim, ic, isn, dx);
        } else {
            const float* lwl = lw + (size_t)(i / 2) * kCE * kCE * kK;
            k_disco<kCE, kCE, 8><<<nb((long long)kNP * 8), B, 0, stream>>>(
                h, kNP, proc_idx, proc_vals, lwl, dx, kNP);
        }
        k_mlp1<<<nb((long long)kHD * kNP), B, 0, stream>>>(m1 + (size_t)i * kHD * kCE, dx, dx1);
        k_mlp2<<<nb((long long)kCE * kNP), B, 0, stream>>>(m2 + (size_t)i * kCE * kHD, ls + (size_t)i * kCE, dx1, h);
    }

    // decoder: upsample then disco conv
    k_upsample<<<nb((long long)kCE * kNPF), B, 0, stream>>>(h, li0, li1, lwt, oi0, oi1, owt, u);
    k_dconv<<<nb((long long)kNPF * 2), B, 0, stream>>>(u, dec_idx, dec_vals, dwT, out);
}

// Round 3
// 888.497 us; speedup vs baseline: 1.2528x; 1.2528x over previous
//
#include <hip/hip_runtime.h>
#include <math.h>

// ---- problem constants ----
constexpr int kHF = 361, kWF = 720;       // full grid
constexpr int kHP = 90,  kWP = 180;       // processor grid
constexpr int kCIN = 26, kCE = 48, kCOUT = 24;
constexpr int kK = 9, kNB = 6;
constexpr int kL = 90, kM = 90;
constexpr int kNL = 4, kHD = 96;
constexpr int kNP  = kHP * kWP;           // 16200
constexpr int kNPF = kHF * kWF;           // 259920

#ifndef M_PI
#define M_PI 3.14159265358979323846
#endif

// ---------------- precompute: DFT tables ----------------
__global__ __launch_bounds__(256) void k_tables(float* __restrict__ fc, float* __restrict__ fs,
                                                float* __restrict__ ic, float* __restrict__ isn) {
    int t = blockIdx.x * 256 + threadIdx.x;
    if (t >= kM * kWP) return;
    int m = t / kWP, w = t % kWP;
    double th = (2.0 * M_PI / (double)kWP) * (double)(m * w);
    double c = cos(th), s = sin(th);
    fc[w * kM + m] = (float)(c / (double)kWP);
    fs[w * kM + m] = (float)(-s / (double)kWP);
    float sc = (m == 0) ? 1.0f : 2.0f;
    ic[m * kWP + w] = sc * (float)c;
    isn[m * kWP + w] = sc * (float)s;
}

// transpose Legendre matrices for coalesced m-reads
__global__ __launch_bounds__(256) void k_trans(const float* __restrict__ P, float* __restrict__ PT, int mode) {
    int t = blockIdx.x * 256 + threadIdx.x;
    if (t >= kL * kM * kHP) return;
    int l = t / (kM * kHP);
    int r = t % (kM * kHP);
    int m = r / kHP;
    int tt = r % kHP;
    float v = P[t];
    if (mode == 0) PT[(l * kHP + tt) * kM + m] = v;
    else           PT[(tt * kL + l) * kM + m] = v;
}

// decoder weight transpose: dwT[(i*24 + o)*9 + k] = dw[(o*48+i)*9+k]
__global__ __launch_bounds__(256) void k_wtrans(const float* __restrict__ dw, float* __restrict__ dwT) {
    int t = blockIdx.x * 256 + threadIdx.x;
    if (t >= kCOUT * kCE * kK) return;
    int k = t % kK;
    int i = (t / kK) % kCE;
    int o = t / (kK * kCE);
    dwT[((size_t)i * kCOUT + o) * kK + k] = dw[t];
}

// ---------------- disco conv (encoder / processor) ----------------
template <int TCIN, int TCOUT, int OG>
__global__ __launch_bounds__(256) void k_disco(const float* __restrict__ src, int srcStride,
                                               const int* __restrict__ idx, const float* __restrict__ vals,
                                               const float* __restrict__ w, float* __restrict__ out, int np) {
    int gt = blockIdx.x * 256 + threadIdx.x;
    if (gt >= np * OG) return;
    int p = gt % np;
    int og = gt / np;
    constexpr int OC = TCOUT / OG;

    int qi[kNB];
#pragma unroll
    for (int n = 0; n < kNB; n++) qi[n] = idx[p * kNB + n];

    float vv[kK][kNB];
#pragma unroll
    for (int k = 0; k < kK; k++) {
        const float* vp = vals + ((size_t)k * np + p) * kNB;
#pragma unroll
        for (int n = 0; n < kNB; n += 2) {
            float2 v2 = *(const float2*)(vp + n);
            vv[k][n] = v2.x; vv[k][n + 1] = v2.y;
        }
    }

    float acc[OC];
#pragma unroll
    for (int o = 0; o < OC; o++) acc[o] = 0.0f;

    const float* wbase = w + (size_t)og * OC * TCIN * kK;

    for (int i = 0; i < TCIN; i++) {
        float xg[kNB];
#pragma unroll
        for (int n = 0; n < kNB; n++) xg[n] = src[i * srcStride + qi[n]];
        float z[kK];
#pragma unroll
        for (int k = 0; k < kK; k++) {
            float zz = 0.0f;
#pragma unroll
            for (int n = 0; n < kNB; n++) zz = fmaf(vv[k][n], xg[n], zz);
            z[k] = zz;
        }
#pragma unroll
        for (int o = 0; o < OC; o++) {
            const float* wp = wbase + ((size_t)o * TCIN + i) * kK;
            float s = acc[o];
#pragma unroll
            for (int k = 0; k < kK; k++) s = fmaf(wp[k], z[k], s);
            acc[o] = s;
        }
    }
#pragma unroll
    for (int o = 0; o < OC; o++) out[(size_t)(og * OC + o) * np + p] = acc[o];
}

// ---------------- spectral pipeline ----------------
__global__ __launch_bounds__(256) void k_rfft(const float* __restrict__ g, const float* __restrict__ fc,
                                              const float* __restrict__ fs, float* __restrict__ xre,
                                              float* __restrict__ xim) {
    int t = blockIdx.x * 256 + threadIdx.x;
    if (t >= kCE * kHP * kM) return;
    int m = t % kM;
    int row = t / kM;
    const float* gr = g + (size_t)row * kWP;
    float ar = 0.0f, ai = 0.0f;
    for (int w = 0; w < kWP; w++) {
        float gv = gr[w];
        ar = fmaf(gv, fc[w * kM + m], ar);
        ai = fmaf(gv, fs[w * kM + m], ai);
    }
    xre[t] = ar;
    xim[t] = ai;
}

__global__ __launch_bounds__(256) void k_sht(const float* __restrict__ PwT, const float* __restrict__ xre,
                                             const float* __restrict__ xim, float* __restrict__ cre,
                                             float* __restrict__ cim) {
    int t = blockIdx.x * 256 + threadIdx.x;
    if (t >= kCE * kL * kM) return;
    int m = t % kM;
    int l = (t / kM) % kL;
    int c = t / (kM * kL);
    float ar = 0.0f, ai = 0.0f;
    for (int tt = 0; tt < kHP; tt++) {
        float pv = PwT[((size_t)l * kHP + tt) * kM + m];
        ar = fmaf(pv, xre[((size_t)c * kHP + tt) * kM + m], ar);
        ai = fmaf(pv, xim[((size_t)c * kHP + tt) * kM + m], ai);
    }
    cre[t] = ar;
    cim[t] = ai;
}

__global__ __launch_bounds__(256) void k_gmix(const float* __restrict__ gwl, const float* __restrict__ cre,
                                              const float* __restrict__ cim, float* __restrict__ ore,
                                              float* __restrict__ oim) {
    int t = blockIdx.x * 256 + threadIdx.x;
    if (t >= kCE * kL * kM) return;
    int m = t % kM;
    int l = (t / kM) % kL;
    int o = t / (kM * kL);
    float ar = 0.0f, ai = 0.0f;
    for (int i = 0; i < kCE; i++) {
        float gv = gwl[((size_t)o * kCE + i) * kL + l];
        ar = fmaf(gv, cre[((size_t)i * kL + l) * kM + m], ar);
        ai = fmaf(gv, cim[((size_t)i * kL + l) * kM + m], ai);
    }
    ore[t] = ar;
    oim[t] = ai;
}

__global__ __launch_bounds__(256) void k_isht(const float* __restrict__ PiT, const float* __restrict__ cre,
                                              const float* __restrict__ cim, float* __restrict__ xre,
                                              float* __restrict__ xim) {
    int t = blockIdx.x * 256 + threadIdx.x;
    if (t >= kCE * kHP * kM) return;
    int m = t % kM;
    int tt = (t / kM) % kHP;
    int c = t / (kM * kHP);
    float ar = 0.0f, ai = 0.0f;
    for (int l = 0; l < kL; l++) {
        float pv = PiT[((size_t)tt * kL + l) * kM + m];
        ar = fmaf(pv, cre[((size_t)c * kL + l) * kM + m], ar);
        ai = fmaf(pv, cim[((size_t)c * kL + l) * kM + m], ai);
    }
    xre[t] = ar;
    xim[t] = ai;
}

__global__ __launch_bounds__(256) void k_irfft(const float* __restrict__ xre, const float* __restrict__ xim,
                                               const float* __restrict__ ic, const float* __restrict__ isn,
                                               float* __restrict__ dx) {
    int t = blockIdx.x * 256 + threadIdx.x;
    if (t >= kCE * kHP * kWP) return;
    int w = t % kWP;
    int row = t / kWP;
    const float* xr = xre + (size_t)row * kM;
    const float* xi = xim + (size_t)row * kM;
    float a = 0.0f;
    for (int m = 0; m < kM; m++) {
        a = fmaf(xr[m], ic[m * kWP + w], a);
        a = fmaf(-xi[m], isn[m * kWP + w], a);
    }
    dx[t] = a;
}

// ---------------- MLP ----------------
__device__ __forceinline__ float gelu_tanh(float x) {
    float x3 = x * x * x;
    float t = tanhf(0.7978845608028654f * (x + 0.044715f * x3));
    return 0.5f * x * (1.0f + t);
}

__global__ __launch_bounds__(256) void k_mlp1(const float* __restrict__ m1w, const float* __restrict__ dx,
                                              float* __restrict__ dx1) {
    int t = blockIdx.x * 256 + threadIdx.x;
    if (t >= kHD * kNP) return;
    int p = t % kNP;
    int hh = t / kNP;
    float a = 0.0f;
    for (int i = 0; i < kCE; i++) a = fmaf(m1w[hh * kCE + i], dx[(size_t)i * kNP + p], a);
    dx1[t] = gelu_tanh(a);
}

__global__ __launch_bounds__(256) void k_mlp2(const float* __restrict__ m2w, const float* __restrict__ lsw,
                                              const float* __restrict__ dx1, float* __restrict__ h) {
    int t = blockIdx.x * 256 + threadIdx.x;
    if (t >= kCE * kNP) return;
    int p = t % kNP;
    int o = t / kNP;
    float a = 0.0f;
    for (int j = 0; j < kHD; j++) a = fmaf(m2w[o * kHD + j], dx1[(size_t)j * kNP + p], a);
    h[t] = h[t] + lsw[o] * a;
}

// ---------------- decoder: fused upsample + disco conv, LDS-tiled ----------------
// Exploits the analytic structure of dec_psi_idx (identity lat/lon mapping on the
// full grid): neighbor n of point (lat,lon) is (clip(lat+dy[n]), (lon+dx[n])%720)
// with (dy,dx) in {(0,0),(0,1),(0,-1),(1,0),(-1,0),(1,1)}.
// Block = 240 output points of one latitude row. u tile (3 rows x 242 lon) is
// interpolated from h directly into LDS in 16-channel chunks.
constexpr int kT  = 240;       // outputs per block
constexpr int kCH = 16;        // channel chunk
constexpr int kTL = kT + 2;    // staged lon extent
constexpr int kTLP = kTL + 2;  // padded LDS stride

__global__ __launch_bounds__(256) void k_dconv_t(const float* __restrict__ h,
                                                 const float* __restrict__ dvals,
                                                 const float* __restrict__ dwT,
                                                 const int* __restrict__ li0, const int* __restrict__ li1,
                                                 const float* __restrict__ lwt, const int* __restrict__ oi0,
                                                 const int* __restrict__ oi1, const float* __restrict__ owt,
                                                 float* __restrict__ out) {
    __shared__ float uld[kCH][3][kTLP];  // 16*3*244*4 = 46.9 KB

    int blk = blockIdx.x;
    int lat = blk / 3;
    int seg = blk % 3;
    int lon0 = seg * kT;
    int tid = threadIdx.x;

    // latitude interp params for tile rows r=0,1,2 -> global lat clip(lat-1+r)
    int a0[3], a1[3];
    float aw[3];
#pragma unroll
    for (int r = 0; r < 3; r++) {
        int Lr = lat - 1 + r;
        Lr = Lr < 0 ? 0 : (Lr > kHF - 1 ? kHF - 1 : Lr);
        a0[r] = li0[Lr]; a1[r] = li1[Lr]; aw[r] = lwt[Lr];
    }

    // longitude interp params for this thread's staged column lx = tid
    int o0 = 0, o1 = 0;
    float ow = 0.0f;
    if (tid < kTL) {
        int lm = (lon0 - 1 + tid + kWF) % kWF;
        o0 = oi0[lm]; o1 = oi1[lm]; ow = owt[lm];
    }

    int p = lat * kWF + lon0 + tid;  // valid iff tid < kT

    // psi vals in registers (independent of channel)
    float vv[kK][kNB];
    if (tid < kT) {
#pragma unroll
        for (int k = 0; k < kK; k++) {
            const float* vp = dvals + ((size_t)k * kNPF + p) * kNB;
#pragma unroll
            for (int n = 0; n < kNB; n += 2) {
                float2 v2 = *(const float2*)(vp + n);
                vv[k][n] = v2.x; vv[k][n + 1] = v2.y;
            }
        }
    }

    float acc[kCOUT];
#pragma unroll
    for (int o = 0; o < kCOUT; o++) acc[o] = 0.0f;

    for (int c0 = 0; c0 < kCE; c0 += kCH) {
        __syncthreads();
        // phase A: interpolate u tile chunk into LDS
        if (tid < kTL) {
#pragma unroll
            for (int r = 0; r < 3; r++) {
                const float* h00 = h + (size_t)c0 * kNP + a0[r] * kWP;
                const float* h10 = h + (size_t)c0 * kNP + a1[r] * kWP;
                float awr = aw[r];
#pragma unroll 4
                for (int ii = 0; ii < kCH; ii++) {
                    float v00 = h00[ii * kNP + o0], v01 = h00[ii * kNP + o1];
                    float v10 = h10[ii * kNP + o0], v11 = h10[ii * kNP + o1];
                    float lo = fmaf(ow, v01 - v00, v00);
                    float hi = fmaf(ow, v11 - v10, v10);
                    uld[ii][r][tid] = fmaf(awr, hi - lo, lo);
                }
            }
        }
        __syncthreads();
        // phase B: gather from LDS + contract
        if (tid < kT) {
            for (int ii = 0; ii < kCH; ii++) {
                int i = c0 + ii;
                float xg[kNB];
                xg[0] = uld[ii][1][tid + 1];  // ( 0, 0)
                xg[1] = uld[ii][1][tid + 2];  // ( 0, 1)
                xg[2] = uld[ii][1][tid + 0];  // ( 0,-1)
                xg[3] = uld[ii][2][tid + 1];  // ( 1, 0)
                xg[4] = uld[ii][0][tid + 1];  // (-1, 0)
                xg[5] = uld[ii][2][tid + 2];  // ( 1, 1)
                float z[kK];
#pragma unroll
                for (int k = 0; k < kK; k++) {
                    float zz = 0.0f;
#pragma unroll
                    for (int n = 0; n < kNB; n++) zz = fmaf(vv[k][n], xg[n], zz);
                    z[k] = zz;
                }
                const float* wp = dwT + (size_t)i * kCOUT * kK;
#pragma unroll
                for (int o = 0; o < kCOUT; o++) {
                    float s = acc[o];
#pragma unroll
                    for (int k = 0; k < kK; k++) s = fmaf(wp[o * kK + k], z[k], s);
                    acc[o] = s;
                }
            }
        }
    }

    if (tid < kT) {
#pragma unroll
        for (int o = 0; o < kCOUT; o++) out[(size_t)o * kNPF + p] = acc[o];
    }
}

// ---------------- host launcher ----------------
extern "C" void kernel_launch(void* const* d_in, const int* in_sizes, int n_in,
                              void* d_out, int out_size, void* d_ws, size_t ws_size,
                              hipStream_t stream) {
    const float* x         = (const float*)d_in[0];
    const int*   enc_idx   = (const int*)d_in[1];
    const float* enc_vals  = (const float*)d_in[2];
    const float* enc_w     = (const float*)d_in[3];
    const int*   proc_idx  = (const int*)d_in[4];
    const float* proc_vals = (const float*)d_in[5];
    const float* lw        = (const float*)d_in[6];
    const float* gw        = (const float*)d_in[7];
    const float* Pw        = (const float*)d_in[8];
    const float* Pi        = (const float*)d_in[9];
    const float* m1        = (const float*)d_in[10];
    const float* m2        = (const float*)d_in[11];
    const float* ls        = (const float*)d_in[12];
    const int*   li0       = (const int*)d_in[13];
    const int*   li1       = (const int*)d_in[14];
    const float* lwt       = (const float*)d_in[15];
    const int*   oi0       = (const int*)d_in[16];
    const int*   oi1       = (const int*)d_in[17];
    const float* owt       = (const float*)d_in[18];
    const int*   dec_idx   = (const int*)d_in[19];
    const float* dec_vals  = (const float*)d_in[20];
    const float* dec_w     = (const float*)d_in[21];
    float* out = (float*)d_out;
    (void)dec_idx;

    float* ws = (float*)d_ws;
    size_t off = 0;
    auto alloc = [&](size_t n) { float* p = ws + off; off += n; return p; };
    float* h    = alloc((size_t)kCE * kNP);
    float* xre  = alloc((size_t)kCE * kHP * kM);
    float* xim  = alloc((size_t)kCE * kHP * kM);
    float* cre  = alloc((size_t)kCE * kL * kM);
    float* cim  = alloc((size_t)kCE * kL * kM);
    float* c2re = alloc((size_t)kCE * kL * kM);
    float* c2im = alloc((size_t)kCE * kL * kM);
    float* dx   = alloc((size_t)kCE * kNP);
    float* dx1  = alloc((size_t)kHD * kNP);
    float* fc   = alloc((size_t)kM * kWP);
    float* fs   = alloc((size_t)kM * kWP);
    float* ic   = alloc((size_t)kM * kWP);
    float* isn  = alloc((size_t)kM * kWP);
    float* PwT  = alloc((size_t)kL * kM * kHP);
    float* PiT  = alloc((size_t)kL * kM * kHP);
    float* dwT  = alloc((size_t)kCOUT * kCE * kK);
    (void)ws_size; (void)in_sizes; (void)n_in; (void)out_size;

    dim3 B(256);
    auto nb = [](long long n) { return dim3((unsigned)((n + 255) / 256)); };

    k_tables<<<nb(kM * kWP), B, 0, stream>>>(fc, fs, ic, isn);
    k_trans<<<nb((long long)kL * kM * kHP), B, 0, stream>>>(Pw, PwT, 0);
    k_trans<<<nb((long long)kL * kM * kHP), B, 0, stream>>>(Pi, PiT, 1);
    k_wtrans<<<nb((long long)kCOUT * kCE * kK), B, 0, stream>>>(dec_w, dwT);

    // encoder
    k_disco<kCIN, kCE, 8><<<nb((long long)kNP * 8), B, 0, stream>>>(
        x, kNPF, enc_idx, enc_vals, enc_w, h, kNP);

    for (int i = 0; i < kNL; i++) {
        if (i % 2 == 0) {
            const float* gwl = gw + (size_t)(i / 2) * kCE * kCE * kL;
            k_rfft<<<nb((long long)kCE * kHP * kM), B, 0, stream>>>(h, fc, fs, xre, xim);
            k_sht<<<nb((long long)kCE * kL * kM), B, 0, stream>>>(PwT, xre, xim, cre, cim);
            k_gmix<<<nb((long long)kCE * kL * kM), B, 0, stream>>>(gwl, cre, cim, c2re, c2im);
            k_isht<<<nb((long long)kCE * kHP * kM), B, 0, stream>>>(PiT, c2re, c2im, xre, xim);
            k_irfft<<<nb((long long)kCE * kHP * kWP), B, 0, stream>>>(xre, xim, ic, isn, dx);
        } else {
            const float* lwl = lw + (size_t)(i / 2) * kCE * kCE * kK;
            k_disco<kCE, kCE, 8><<<nb((long long)kNP * 8), B, 0, stream>>>(
                h, kNP, proc_idx, proc_vals, lwl, dx, kNP);
        }
        k_mlp1<<<nb((long long)kHD * kNP), B, 0, stream>>>(m1 + (size_t)i * kHD * kCE, dx, dx1);
        k_mlp2<<<nb((long long)kCE * kNP), B, 0, stream>>>(m2 + (size_t)i * kCE * kHD, ls + (size_t)i * kCE, dx1, h);
    }

    // decoder: fused upsample + disco conv (LDS-tiled)
    k_dconv_t<<<dim3(kHF * 3), B, 0, stream>>>(h, dec_vals, dwT,
                                               li0, li1, lwt, oi0, oi1, owt, out);
}